// Round 3
// baseline (359.128 us; speedup 1.0000x reference)
//
#include <hip/hip_runtime.h>

#define DIM 1024
#define SEQ 2048
#define SCALE 0.125f

typedef unsigned short ushort_t;
typedef unsigned int u32;
typedef __attribute__((ext_vector_type(8))) short short8;
typedef __attribute__((ext_vector_type(8))) unsigned short ushort8;
typedef __attribute__((ext_vector_type(4))) float f32x4;

__device__ __forceinline__ ushort_t f2bf(float x) {
    u32 u = __float_as_uint(x);
    u32 r = (u + 0x7fffu + ((u >> 16) & 1u)) >> 16;
    return (ushort_t)r;
}

__device__ __forceinline__ void gload16(const void* g, void* l) {
    __builtin_amdgcn_global_load_lds(
        (const __attribute__((address_space(1))) u32*)g,
        (__attribute__((address_space(3))) u32*)l, 16, 0, 0);
}

// XOR-swizzled element index within a [rows][64-bf16] tile (8-elem groups)
__device__ __forceinline__ int swz8(int row, int col) {
    return row * 64 + ((((col >> 3) ^ (row & 7)) << 3) | (col & 7));
}

// ---------------------------------------------------------------------------
// fp32 -> bf16 conversion (vectorized, grid-stride)
// ---------------------------------------------------------------------------
__global__ __launch_bounds__(256) void cvt_bf16(const float* __restrict__ in,
                                                ushort_t* __restrict__ out, int n8) {
    for (int i = blockIdx.x * blockDim.x + threadIdx.x; i < n8; i += gridDim.x * blockDim.x) {
        const float4 a = ((const float4*)in)[2 * i];
        const float4 b = ((const float4*)in)[2 * i + 1];
        ushort8 o;
        o[0] = f2bf(a.x); o[1] = f2bf(a.y); o[2] = f2bf(a.z); o[3] = f2bf(a.w);
        o[4] = f2bf(b.x); o[5] = f2bf(b.y); o[6] = f2bf(b.z); o[7] = f2bf(b.w);
        ((ushort8*)out)[i] = o;
    }
}

// ---------------------------------------------------------------------------
// bf16 GEMM, m97 structure: C[m,n] = sum_k A[m,k] * B[n,k]  (B^T layout)
// 128x128 tile, BK=64, 4 waves, global_load_lds width 16, linear LDS.
// EPI 0: scatter bf16 into qkv buffer [3][bh][s][64]
// EPI 1: fp32 out + bias
// ---------------------------------------------------------------------------
template <int EPI>
__global__ __launch_bounds__(256) void gemm_bt(const ushort_t* __restrict__ A,
                                               const ushort_t* __restrict__ B,
                                               const float* __restrict__ bias,
                                               ushort_t* __restrict__ outb,
                                               float* __restrict__ outf) {
    __shared__ ushort_t As[128 * 64];
    __shared__ ushort_t Bs[128 * 64];
    const int t = threadIdx.x;
    const int m0 = blockIdx.y * 128, n0 = blockIdx.x * 128;
    const int w = t >> 6, lane = t & 63, k15 = lane & 15, g = lane >> 4;
    const int wm = (w >> 1) * 64, wn = (w & 1) * 64;
    const int srow = t >> 3, scol = (t & 7) * 8;

    f32x4 acc[4][4] = {};

    for (int k0 = 0; k0 < 1024; k0 += 64) {
        __syncthreads();
        #pragma unroll
        for (int i = 0; i < 4; ++i) {
            gload16(&A[(size_t)(m0 + i * 32 + srow) * 1024 + k0 + scol],
                    ((char*)As) + i * 4096 + t * 16);
            gload16(&B[(size_t)(n0 + i * 32 + srow) * 1024 + k0 + scol],
                    ((char*)Bs) + i * 4096 + t * 16);
        }
        __syncthreads();
        #pragma unroll
        for (int ks = 0; ks < 2; ++ks) {
            short8 af[4], bf[4];
            #pragma unroll
            for (int i = 0; i < 4; ++i) {
                af[i] = *(const short8*)&As[(wm + i * 16 + k15) * 64 + ks * 32 + g * 8];
                bf[i] = *(const short8*)&Bs[(wn + i * 16 + k15) * 64 + ks * 32 + g * 8];
            }
            #pragma unroll
            for (int mi = 0; mi < 4; ++mi)
                #pragma unroll
                for (int ni = 0; ni < 4; ++ni)
                    acc[mi][ni] = __builtin_amdgcn_mfma_f32_16x16x32_bf16(
                        af[mi], bf[ni], acc[mi][ni], 0, 0, 0);
        }
    }

    if (EPI == 0) {
        #pragma unroll
        for (int mi = 0; mi < 4; ++mi) {
            #pragma unroll
            for (int r = 0; r < 4; ++r) {
                const int m = m0 + wm + mi * 16 + g * 4 + r;
                const int b = m >> 11, s = m & 2047;
                #pragma unroll
                for (int ni = 0; ni < 4; ++ni) {
                    const int e = n0 + wn + ni * 16 + k15;
                    const int qi = e >> 10, h = (e >> 6) & 15, hd = e & 63;
                    outb[((size_t)(qi * 64 + b * 16 + h) * SEQ + s) * 64 + hd] =
                        f2bf(acc[mi][ni][r]);
                }
            }
        }
    } else {
        #pragma unroll
        for (int mi = 0; mi < 4; ++mi) {
            #pragma unroll
            for (int r = 0; r < 4; ++r) {
                const size_t m = m0 + wm + mi * 16 + g * 4 + r;
                #pragma unroll
                for (int ni = 0; ni < 4; ++ni) {
                    const int e = n0 + wn + ni * 16 + k15;
                    outf[m * 1024 + e] = acc[mi][ni][r] + bias[e];
                }
            }
        }
    }
}

// ---------------------------------------------------------------------------
// Flash attention, bf16 MFMA. 256 threads = 4 waves; wave owns 32 q-rows.
// QBLK=128, KVBLK=64. K staged via pre-swizzled global_load_lds; V reg-staged
// transposed; P through per-wave LDS. All LDS tiles XOR-swizzled (8-elem).
// ---------------------------------------------------------------------------
__global__ __launch_bounds__(256) void attn_mfma(const ushort_t* __restrict__ qkv,
                                                 ushort_t* __restrict__ aout) {
    __shared__ ushort_t Ks[64 * 64];
    __shared__ ushort_t Vt[64 * 64];   // transposed: [d][key]
    __shared__ ushort_t Pl[4 * 32 * 64];

    const int t = threadIdx.x, w = t >> 6, lane = t & 63;
    const int k15 = lane & 15, g = lane >> 4;
    const int q0 = blockIdx.x * 128, bh = blockIdx.y;
    const ushort_t* Qp = qkv + (size_t)bh * SEQ * 64;
    const ushort_t* Kp = qkv + (size_t)(64 + bh) * SEQ * 64;
    const ushort_t* Vp = qkv + (size_t)(128 + bh) * SEQ * 64;
    const int wq0 = q0 + w * 32;
    ushort_t* Pw = Pl + w * (32 * 64);

    // Q fragments, resident whole kernel
    short8 qf[2][2];
    #pragma unroll
    for (int mt = 0; mt < 2; ++mt)
        #pragma unroll
        for (int ks = 0; ks < 2; ++ks)
            qf[mt][ks] = *(const short8*)&Qp[(size_t)(wq0 + mt * 16 + k15) * 64 + ks * 32 + g * 8];

    f32x4 o[2][4] = {};
    float mi[2][4], li[2][4];
    #pragma unroll
    for (int mt = 0; mt < 2; ++mt)
        #pragma unroll
        for (int r = 0; r < 4; ++r) { mi[mt][r] = -1e30f; li[mt][r] = 0.f; }

    for (int kt = 0; kt < SEQ / 64; ++kt) {
        const int kb = kt * 64;
        __syncthreads();
        // stage K: linear LDS dest, pre-swizzled global source
        #pragma unroll
        for (int i = 0; i < 2; ++i) {
            const int row = i * 32 + (t >> 3);
            const int scb = (t & 7) ^ (row & 7);
            gload16(&Kp[(size_t)(kb + row) * 64 + scb * 8],
                    ((char*)Ks) + i * 4096 + t * 16);
        }
        // stage V transposed (reg -> swizzled ds writes)
        {
            const int key = t & 63;
            short8 v0 = *(const short8*)&Vp[(size_t)(kb + key) * 64 + (t >> 6) * 8];
            short8 v1 = *(const short8*)&Vp[(size_t)(kb + key) * 64 + (t >> 6) * 8 + 32];
            #pragma unroll
            for (int j = 0; j < 8; ++j) {
                Vt[swz8((t >> 6) * 8 + j, key)]      = (ushort_t)v0[j];
                Vt[swz8((t >> 6) * 8 + 32 + j, key)] = (ushort_t)v1[j];
            }
        }
        __syncthreads();

        // QK^T: S[32 q][64 key]
        f32x4 s[2][4] = {};
        #pragma unroll
        for (int ks = 0; ks < 2; ++ks) {
            short8 kf[4];
            #pragma unroll
            for (int nt = 0; nt < 4; ++nt)
                kf[nt] = *(const short8*)&Ks[swz8(nt * 16 + k15, ks * 32 + g * 8)];
            #pragma unroll
            for (int mt = 0; mt < 2; ++mt)
                #pragma unroll
                for (int nt = 0; nt < 4; ++nt)
                    s[mt][nt] = __builtin_amdgcn_mfma_f32_16x16x32_bf16(
                        qf[mt][ks], kf[nt], s[mt][nt], 0, 0, 0);
        }

        // online softmax + P -> LDS (bf16)
        #pragma unroll
        for (int mt = 0; mt < 2; ++mt) {
            #pragma unroll
            for (int r = 0; r < 4; ++r) {
                float x0 = s[mt][0][r] * SCALE, x1 = s[mt][1][r] * SCALE;
                float x2 = s[mt][2][r] * SCALE, x3 = s[mt][3][r] * SCALE;
                float rm = fmaxf(fmaxf(x0, x1), fmaxf(x2, x3));
                rm = fmaxf(rm, __shfl_xor(rm, 1));
                rm = fmaxf(rm, __shfl_xor(rm, 2));
                rm = fmaxf(rm, __shfl_xor(rm, 4));
                rm = fmaxf(rm, __shfl_xor(rm, 8));
                const float mnew = fmaxf(mi[mt][r], rm);
                const float corr = __expf(mi[mt][r] - mnew);
                mi[mt][r] = mnew;
                const float e0 = __expf(x0 - mnew), e1 = __expf(x1 - mnew);
                const float e2 = __expf(x2 - mnew), e3 = __expf(x3 - mnew);
                float rs = (e0 + e1) + (e2 + e3);
                rs += __shfl_xor(rs, 1);
                rs += __shfl_xor(rs, 2);
                rs += __shfl_xor(rs, 4);
                rs += __shfl_xor(rs, 8);
                li[mt][r] = li[mt][r] * corr + rs;
                const int row = mt * 16 + g * 4 + r;
                Pw[swz8(row, 0 * 16 + k15)] = f2bf(e0);
                Pw[swz8(row, 1 * 16 + k15)] = f2bf(e1);
                Pw[swz8(row, 2 * 16 + k15)] = f2bf(e2);
                Pw[swz8(row, 3 * 16 + k15)] = f2bf(e3);
                #pragma unroll
                for (int dt = 0; dt < 4; ++dt) o[mt][dt][r] *= corr;
            }
        }

        // PV: O[32 q][64 d] += P[32][64] * V[64][64]   (B^T = Vt)
        #pragma unroll
        for (int ks = 0; ks < 2; ++ks) {
            short8 pa[2], vb[4];
            #pragma unroll
            for (int mt = 0; mt < 2; ++mt)
                pa[mt] = *(const short8*)&Pw[swz8(mt * 16 + k15, ks * 32 + g * 8)];
            #pragma unroll
            for (int dt = 0; dt < 4; ++dt)
                vb[dt] = *(const short8*)&Vt[swz8(dt * 16 + k15, ks * 32 + g * 8)];
            #pragma unroll
            for (int mt = 0; mt < 2; ++mt)
                #pragma unroll
                for (int dt = 0; dt < 4; ++dt)
                    o[mt][dt] = __builtin_amdgcn_mfma_f32_16x16x32_bf16(
                        pa[mt], vb[dt], o[mt][dt], 0, 0, 0);
        }
    }

    // epilogue: out rows [b, s, h*64 + d], bf16
    const int b = bh >> 4, h = bh & 15;
    #pragma unroll
    for (int mt = 0; mt < 2; ++mt) {
        #pragma unroll
        for (int r = 0; r < 4; ++r) {
            const float inv = 1.0f / li[mt][r];
            const int q = wq0 + mt * 16 + g * 4 + r;
            const size_t rowo = ((size_t)b * SEQ + q) * DIM + h * 64;
            #pragma unroll
            for (int dt = 0; dt < 4; ++dt)
                aout[rowo + dt * 16 + k15] = f2bf(o[mt][dt][r] * inv);
        }
    }
}

// ---------------------------------------------------------------------------
extern "C" void kernel_launch(void* const* d_in, const int* in_sizes, int n_in,
                              void* d_out, int out_size, void* d_ws, size_t ws_size,
                              hipStream_t stream) {
    const float* x     = (const float*)d_in[0];   // [4,2048,1024]
    const float* w_qkv = (const float*)d_in[1];   // [3072,1024]
    const float* w_out = (const float*)d_in[2];   // [1024,1024]
    const float* b_out = (const float*)d_in[3];   // [1024]
    float* out = (float*)d_out;

    char* ws = (char*)d_ws;
    ushort_t* xb    = (ushort_t*)ws;                          // 16 MB
    ushort_t* wqkvb = (ushort_t*)(ws + (size_t)16 * 1024 * 1024);   // 6 MB
    ushort_t* woutb = (ushort_t*)(ws + (size_t)22 * 1024 * 1024);   // 2 MB
    ushort_t* qkvb  = (ushort_t*)(ws + (size_t)24 * 1024 * 1024);   // 48 MB: [3][64][2048][64]
    ushort_t* aob   = (ushort_t*)(ws + (size_t)72 * 1024 * 1024);   // 16 MB: [8192][1024]

    cvt_bf16<<<1024, 256, 0, stream>>>(x,     xb,    8192 * 1024 / 8);
    cvt_bf16<<<512,  256, 0, stream>>>(w_qkv, wqkvb, 3072 * 1024 / 8);
    cvt_bf16<<<256,  256, 0, stream>>>(w_out, woutb, 1024 * 1024 / 8);

    gemm_bt<0><<<dim3(24, 64), 256, 0, stream>>>(xb, wqkvb, nullptr, qkvb, nullptr);
    attn_mfma<<<dim3(16, 64), 256, 0, stream>>>(qkvb, aob);
    gemm_bt<1><<<dim3(8, 64), 256, 0, stream>>>(aob, woutb, b_out, nullptr, out);
}

// Round 4
// 256.862 us; speedup vs baseline: 1.3981x; 1.3981x over previous
//
#include <hip/hip_runtime.h>

#define DIM 1024
#define SEQ 2048

typedef unsigned short ushort_t;
typedef unsigned int u32;
typedef __attribute__((ext_vector_type(8))) short short8;
typedef __attribute__((ext_vector_type(8))) unsigned short ushort8;
typedef __attribute__((ext_vector_type(4))) float f32x4;

__device__ __forceinline__ ushort_t f2bf(float x) {
    u32 u = __float_as_uint(x);
    u32 r = (u + 0x7fffu + ((u >> 16) & 1u)) >> 16;
    return (ushort_t)r;
}

__device__ __forceinline__ u32 cvtpk(float lo, float hi) {
    u32 r;
    asm("v_cvt_pk_bf16_f32 %0, %1, %2" : "=v"(r) : "v"(lo), "v"(hi));
    return r;
}

__device__ __forceinline__ void gload16(const void* g, void* l) {
    __builtin_amdgcn_global_load_lds(
        (const __attribute__((address_space(1))) u32*)g,
        (__attribute__((address_space(3))) u32*)l, 16, 0, 0);
}

// XOR-swizzled element index within a [rows][64-bf16] tile (8-elem groups)
__device__ __forceinline__ int swz8(int row, int col) {
    return row * 64 + ((((col >> 3) ^ (row & 7)) << 3) | (col & 7));
}

// ---------------------------------------------------------------------------
// fp32 -> bf16 conversion (vectorized, grid-stride)
// ---------------------------------------------------------------------------
__global__ __launch_bounds__(256) void cvt_bf16(const float* __restrict__ in,
                                                ushort_t* __restrict__ out, int n8) {
    for (int i = blockIdx.x * blockDim.x + threadIdx.x; i < n8; i += gridDim.x * blockDim.x) {
        const float4 a = ((const float4*)in)[2 * i];
        const float4 b = ((const float4*)in)[2 * i + 1];
        ushort8 o;
        o[0] = f2bf(a.x); o[1] = f2bf(a.y); o[2] = f2bf(a.z); o[3] = f2bf(a.w);
        o[4] = f2bf(b.x); o[5] = f2bf(b.y); o[6] = f2bf(b.z); o[7] = f2bf(b.w);
        ((ushort8*)out)[i] = o;
    }
}

// ---------------------------------------------------------------------------
// bf16 GEMM, m97 structure: C[m,n] = sum_k A[m,k] * B[n,k]  (B^T layout)
// EPI 0: scatter bf16 into qkv buffer [3][bh][s][64]; Q part pre-scaled 0.125
// EPI 1: fp32 out + bias
// ---------------------------------------------------------------------------
template <int EPI>
__global__ __launch_bounds__(256) void gemm_bt(const ushort_t* __restrict__ A,
                                               const ushort_t* __restrict__ B,
                                               const float* __restrict__ bias,
                                               ushort_t* __restrict__ outb,
                                               float* __restrict__ outf) {
    __shared__ __align__(16) ushort_t As[128 * 64];
    __shared__ __align__(16) ushort_t Bs[128 * 64];
    const int t = threadIdx.x;
    const int m0 = blockIdx.y * 128, n0 = blockIdx.x * 128;
    const int w = t >> 6, lane = t & 63, k15 = lane & 15, g = lane >> 4;
    const int wm = (w >> 1) * 64, wn = (w & 1) * 64;
    const int srow = t >> 3, scol = (t & 7) * 8;

    f32x4 acc[4][4] = {};

    for (int k0 = 0; k0 < 1024; k0 += 64) {
        __syncthreads();
        #pragma unroll
        for (int i = 0; i < 4; ++i) {
            gload16(&A[(size_t)(m0 + i * 32 + srow) * 1024 + k0 + scol],
                    ((char*)As) + i * 4096 + t * 16);
            gload16(&B[(size_t)(n0 + i * 32 + srow) * 1024 + k0 + scol],
                    ((char*)Bs) + i * 4096 + t * 16);
        }
        __syncthreads();
        #pragma unroll
        for (int ks = 0; ks < 2; ++ks) {
            short8 af[4], bf[4];
            #pragma unroll
            for (int i = 0; i < 4; ++i) {
                af[i] = *(const short8*)&As[(wm + i * 16 + k15) * 64 + ks * 32 + g * 8];
                bf[i] = *(const short8*)&Bs[(wn + i * 16 + k15) * 64 + ks * 32 + g * 8];
            }
            #pragma unroll
            for (int mi = 0; mi < 4; ++mi)
                #pragma unroll
                for (int ni = 0; ni < 4; ++ni)
                    acc[mi][ni] = __builtin_amdgcn_mfma_f32_16x16x32_bf16(
                        af[mi], bf[ni], acc[mi][ni], 0, 0, 0);
        }
    }

    if (EPI == 0) {
        #pragma unroll
        for (int mi = 0; mi < 4; ++mi) {
            #pragma unroll
            for (int r = 0; r < 4; ++r) {
                const int m = m0 + wm + mi * 16 + g * 4 + r;
                const int b = m >> 11, s = m & 2047;
                #pragma unroll
                for (int ni = 0; ni < 4; ++ni) {
                    const int e = n0 + wn + ni * 16 + k15;
                    const int qi = e >> 10, h = (e >> 6) & 15, hd = e & 63;
                    const float scl = (qi == 0) ? 0.125f : 1.0f;  // fold softmax scale into Q (exact)
                    outb[((size_t)(qi * 64 + b * 16 + h) * SEQ + s) * 64 + hd] =
                        f2bf(acc[mi][ni][r] * scl);
                }
            }
        }
    } else {
        #pragma unroll
        for (int mi = 0; mi < 4; ++mi) {
            #pragma unroll
            for (int r = 0; r < 4; ++r) {
                const size_t m = m0 + wm + mi * 16 + g * 4 + r;
                #pragma unroll
                for (int ni = 0; ni < 4; ++ni) {
                    const int e = n0 + wn + ni * 16 + k15;
                    outf[m * 1024 + e] = acc[mi][ni][r] + bias[e];
                }
            }
        }
    }
}

// ---------------------------------------------------------------------------
// Flash attention, bf16 MFMA, SWAPPED operands: S^T = mfma(K, Q) so each lane
// owns one q-row's P values (in-lane softmax); O^T = mfma(V^T, P) keeps
// corr/li lane-local. 256 threads = 4 waves; wave owns 32 q-rows. KVBLK=64.
// ---------------------------------------------------------------------------
__global__ __launch_bounds__(256) void attn_mfma(const ushort_t* __restrict__ qkv,
                                                 ushort_t* __restrict__ aout) {
    __shared__ __align__(16) ushort_t Ks[64 * 64];
    __shared__ __align__(16) ushort_t Vt[64 * 64];   // transposed: [d][key]
    __shared__ __align__(16) ushort_t Pl[4 * 32 * 64];

    const int t = threadIdx.x, w = t >> 6, lane = t & 63;
    const int k15 = lane & 15, g = lane >> 4;
    const int q0 = blockIdx.x * 128, bh = blockIdx.y;
    const ushort_t* Qp = qkv + (size_t)bh * SEQ * 64;
    const ushort_t* Kp = qkv + (size_t)(64 + bh) * SEQ * 64;
    const ushort_t* Vp = qkv + (size_t)(128 + bh) * SEQ * 64;
    const int wq0 = q0 + w * 32;
    ushort_t* Pw = Pl + w * (32 * 64);

    // Q fragments (B-operand: lane&15 = q), resident whole kernel; pre-scaled
    short8 qf[2][2];
    #pragma unroll
    for (int qt = 0; qt < 2; ++qt)
        #pragma unroll
        for (int ks = 0; ks < 2; ++ks)
            qf[qt][ks] = *(const short8*)&Qp[(size_t)(wq0 + qt * 16 + k15) * 64 + ks * 32 + g * 8];

    f32x4 o2[4][2] = {};               // O^T: [d-tile][q-tile], col=q=k15
    float mi[2] = {-1e30f, -1e30f}, li[2] = {0.f, 0.f};

    for (int kt = 0; kt < SEQ / 64; ++kt) {
        const int kb = kt * 64;
        __syncthreads();
        // stage K: linear LDS dest, pre-swizzled global source
        #pragma unroll
        for (int i = 0; i < 2; ++i) {
            const int row = i * 32 + (t >> 3);
            const int scb = (t & 7) ^ (row & 7);
            gload16(&Kp[(size_t)(kb + row) * 64 + scb * 8],
                    ((char*)Ks) + i * 4096 + t * 16);
        }
        // stage V transposed (reg -> swizzled ds writes)
        {
            const int key = t & 63;
            short8 v0 = *(const short8*)&Vp[(size_t)(kb + key) * 64 + (t >> 6) * 8];
            short8 v1 = *(const short8*)&Vp[(size_t)(kb + key) * 64 + (t >> 6) * 8 + 32];
            #pragma unroll
            for (int j = 0; j < 8; ++j) {
                Vt[swz8((t >> 6) * 8 + j, key)]      = (ushort_t)v0[j];
                Vt[swz8((t >> 6) * 8 + 32 + j, key)] = (ushort_t)v1[j];
            }
        }
        __syncthreads();

        // QK^T swapped: S^T[key][q]; lane holds key = mt*16 + g*4 + r, q = qt*16 + k15
        f32x4 s2[4][2] = {};
        #pragma unroll
        for (int ks = 0; ks < 2; ++ks) {
            short8 kf[4];
            #pragma unroll
            for (int mt = 0; mt < 4; ++mt)
                kf[mt] = *(const short8*)&Ks[swz8(mt * 16 + k15, ks * 32 + g * 8)];
            #pragma unroll
            for (int mt = 0; mt < 4; ++mt)
                #pragma unroll
                for (int qt = 0; qt < 2; ++qt)
                    s2[mt][qt] = __builtin_amdgcn_mfma_f32_16x16x32_bf16(
                        kf[mt], qf[qt][ks], s2[mt][qt], 0, 0, 0);
        }

        // in-lane online softmax (16 keys/lane per qt; row spans 4 g-groups)
        float corr[2];
        #pragma unroll
        for (int qt = 0; qt < 2; ++qt) {
            float vm = s2[0][qt][0];
            #pragma unroll
            for (int mt = 0; mt < 4; ++mt)
                #pragma unroll
                for (int r = 0; r < 4; ++r)
                    vm = fmaxf(vm, s2[mt][qt][r]);
            vm = fmaxf(vm, __shfl_xor(vm, 16));
            vm = fmaxf(vm, __shfl_xor(vm, 32));
            const float mnew = fmaxf(mi[qt], vm);
            corr[qt] = __expf(mi[qt] - mnew);
            mi[qt] = mnew;
            float rs = 0.f;
            #pragma unroll
            for (int mt = 0; mt < 4; ++mt)
                #pragma unroll
                for (int r = 0; r < 4; ++r) {
                    const float e = __expf(s2[mt][qt][r] - mnew);
                    s2[mt][qt][r] = e;
                    rs += e;
                }
            rs += __shfl_xor(rs, 16);
            rs += __shfl_xor(rs, 32);
            li[qt] = li[qt] * corr[qt] + rs;
        }

        // P -> LDS [32 q][64 key] per wave (packed b64, swizzled)
        #pragma unroll
        for (int qt = 0; qt < 2; ++qt) {
            const int row = qt * 16 + k15;
            #pragma unroll
            for (int i = 0; i < 4; ++i) {   // keys 16*i + 4*g .. +3
                const u32 lo = cvtpk(s2[i][qt][0], s2[i][qt][1]);
                const u32 hi = cvtpk(s2[i][qt][2], s2[i][qt][3]);
                const int grp = 2 * i + (g >> 1);
                const int idx = row * 64 + ((grp ^ (row & 7)) << 3) + (g & 1) * 4;
                *(uint2*)&Pw[idx] = make_uint2(lo, hi);
            }
        }

        // rescale O
        #pragma unroll
        for (int mt = 0; mt < 4; ++mt)
            #pragma unroll
            for (int qt = 0; qt < 2; ++qt)
                #pragma unroll
                for (int r = 0; r < 4; ++r)
                    o2[mt][qt][r] *= corr[qt];

        // PV swapped: O^T[d][q] += V^T[d][key] * P^T[key][q]
        #pragma unroll
        for (int ks = 0; ks < 2; ++ks) {
            short8 vb[4], pa[2];
            #pragma unroll
            for (int mt = 0; mt < 4; ++mt)
                vb[mt] = *(const short8*)&Vt[swz8(mt * 16 + k15, ks * 32 + g * 8)];
            #pragma unroll
            for (int qt = 0; qt < 2; ++qt)
                pa[qt] = *(const short8*)&Pw[swz8(qt * 16 + k15, ks * 32 + g * 8)];
            #pragma unroll
            for (int mt = 0; mt < 4; ++mt)
                #pragma unroll
                for (int qt = 0; qt < 2; ++qt)
                    o2[mt][qt] = __builtin_amdgcn_mfma_f32_16x16x32_bf16(
                        vb[mt], pa[qt], o2[mt][qt], 0, 0, 0);
        }
    }

    // epilogue: lane owns q = wq0 + qt*16 + k15, d = mt*16 + g*4 + r (packed 8B stores)
    const int b = bh >> 4, h = bh & 15;
    #pragma unroll
    for (int qt = 0; qt < 2; ++qt) {
        const float inv = 1.0f / li[qt];
        const int q = wq0 + qt * 16 + k15;
        const size_t base = ((size_t)b * SEQ + q) * DIM + h * 64;
        #pragma unroll
        for (int mt = 0; mt < 4; ++mt) {
            const u32 lo = cvtpk(o2[mt][qt][0] * inv, o2[mt][qt][1] * inv);
            const u32 hi = cvtpk(o2[mt][qt][2] * inv, o2[mt][qt][3] * inv);
            *(uint2*)&aout[base + mt * 16 + g * 4] = make_uint2(lo, hi);
        }
    }
}

// ---------------------------------------------------------------------------
extern "C" void kernel_launch(void* const* d_in, const int* in_sizes, int n_in,
                              void* d_out, int out_size, void* d_ws, size_t ws_size,
                              hipStream_t stream) {
    const float* x     = (const float*)d_in[0];   // [4,2048,1024]
    const float* w_qkv = (const float*)d_in[1];   // [3072,1024]
    const float* w_out = (const float*)d_in[2];   // [1024,1024]
    const float* b_out = (const float*)d_in[3];   // [1024]
    float* out = (float*)d_out;

    char* ws = (char*)d_ws;
    ushort_t* xb    = (ushort_t*)ws;                                // 16 MB
    ushort_t* wqkvb = (ushort_t*)(ws + (size_t)16 * 1024 * 1024);   // 6 MB
    ushort_t* woutb = (ushort_t*)(ws + (size_t)22 * 1024 * 1024);   // 2 MB
    ushort_t* qkvb  = (ushort_t*)(ws + (size_t)24 * 1024 * 1024);   // 48 MB: [3][64][2048][64]
    ushort_t* aob   = (ushort_t*)(ws + (size_t)72 * 1024 * 1024);   // 16 MB: [8192][1024]

    cvt_bf16<<<1024, 256, 0, stream>>>(x,     xb,    8192 * 1024 / 8);
    cvt_bf16<<<512,  256, 0, stream>>>(w_qkv, wqkvb, 3072 * 1024 / 8);
    cvt_bf16<<<256,  256, 0, stream>>>(w_out, woutb, 1024 * 1024 / 8);

    gemm_bt<0><<<dim3(24, 64), 256, 0, stream>>>(xb, wqkvb, nullptr, qkvb, nullptr);
    attn_mfma<<<dim3(16, 64), 256, 0, stream>>>(qkvb, aob);
    gemm_bt<1><<<dim3(8, 64), 256, 0, stream>>>(aob, woutb, b_out, nullptr, out);
}

// Round 5
// 250.014 us; speedup vs baseline: 1.4364x; 1.0274x over previous
//
#include <hip/hip_runtime.h>

#define DIM 1024
#define SEQ 2048

typedef unsigned short ushort_t;
typedef unsigned int u32;
typedef __attribute__((ext_vector_type(8))) short short8;
typedef __attribute__((ext_vector_type(8))) unsigned short ushort8;
typedef __attribute__((ext_vector_type(4))) float f32x4;

__device__ __forceinline__ ushort_t f2bf(float x) {
    u32 u = __float_as_uint(x);
    u32 r = (u + 0x7fffu + ((u >> 16) & 1u)) >> 16;
    return (ushort_t)r;
}

__device__ __forceinline__ u32 cvtpk(float lo, float hi) {
    u32 r;
    asm("v_cvt_pk_bf16_f32 %0, %1, %2" : "=v"(r) : "v"(lo), "v"(hi));
    return r;
}

__device__ __forceinline__ void gload16(const void* g, void* l) {
    __builtin_amdgcn_global_load_lds(
        (const __attribute__((address_space(1))) u32*)g,
        (__attribute__((address_space(3))) u32*)l, 16, 0, 0);
}

// XOR-swizzled element index within a [rows][64-bf16] tile (8-elem groups)
__device__ __forceinline__ int swz8(int row, int col) {
    return row * 64 + ((((col >> 3) ^ (row & 7)) << 3) | (col & 7));
}

// ---------------------------------------------------------------------------
// fp32 -> bf16 conversion (vectorized, grid-stride)
// ---------------------------------------------------------------------------
__global__ __launch_bounds__(256) void cvt_bf16(const float* __restrict__ in,
                                                ushort_t* __restrict__ out, int n8) {
    for (int i = blockIdx.x * blockDim.x + threadIdx.x; i < n8; i += gridDim.x * blockDim.x) {
        const float4 a = ((const float4*)in)[2 * i];
        const float4 b = ((const float4*)in)[2 * i + 1];
        ushort8 o;
        o[0] = f2bf(a.x); o[1] = f2bf(a.y); o[2] = f2bf(a.z); o[3] = f2bf(a.w);
        o[4] = f2bf(b.x); o[5] = f2bf(b.y); o[6] = f2bf(b.z); o[7] = f2bf(b.w);
        ((ushort8*)out)[i] = o;
    }
}

// ---------------------------------------------------------------------------
// bf16 GEMM, m97 structure: C[m,n] = sum_k A[m,k] * B[n,k]  (B^T layout)
// EPI 0: Q (pre-scaled 0.125) and K -> qk buffer [2][bh][s][64];
//        V -> TRANSPOSED buffer [bh][d=64][s=2048] (uint2-packed stores)
// EPI 1: fp32 out + bias
// ---------------------------------------------------------------------------
template <int EPI>
__global__ __launch_bounds__(256) void gemm_bt(const ushort_t* __restrict__ A,
                                               const ushort_t* __restrict__ B,
                                               const float* __restrict__ bias,
                                               ushort_t* __restrict__ outb,
                                               ushort_t* __restrict__ voutb,
                                               float* __restrict__ outf) {
    __shared__ __align__(16) ushort_t As[128 * 64];
    __shared__ __align__(16) ushort_t Bs[128 * 64];
    const int t = threadIdx.x;
    const int m0 = blockIdx.y * 128, n0 = blockIdx.x * 128;
    const int w = t >> 6, lane = t & 63, k15 = lane & 15, g = lane >> 4;
    const int wm = (w >> 1) * 64, wn = (w & 1) * 64;
    const int srow = t >> 3, scol = (t & 7) * 8;

    f32x4 acc[4][4] = {};

    for (int k0 = 0; k0 < 1024; k0 += 64) {
        __syncthreads();
        #pragma unroll
        for (int i = 0; i < 4; ++i) {
            gload16(&A[(size_t)(m0 + i * 32 + srow) * 1024 + k0 + scol],
                    ((char*)As) + i * 4096 + t * 16);
            gload16(&B[(size_t)(n0 + i * 32 + srow) * 1024 + k0 + scol],
                    ((char*)Bs) + i * 4096 + t * 16);
        }
        __syncthreads();
        #pragma unroll
        for (int ks = 0; ks < 2; ++ks) {
            short8 af[4], bf[4];
            #pragma unroll
            for (int i = 0; i < 4; ++i) {
                af[i] = *(const short8*)&As[(wm + i * 16 + k15) * 64 + ks * 32 + g * 8];
                bf[i] = *(const short8*)&Bs[(wn + i * 16 + k15) * 64 + ks * 32 + g * 8];
            }
            #pragma unroll
            for (int mi = 0; mi < 4; ++mi)
                #pragma unroll
                for (int ni = 0; ni < 4; ++ni)
                    acc[mi][ni] = __builtin_amdgcn_mfma_f32_16x16x32_bf16(
                        af[mi], bf[ni], acc[mi][ni], 0, 0, 0);
        }
    }

    if (EPI == 0) {
        #pragma unroll
        for (int mi = 0; mi < 4; ++mi) {
            const int mbase = m0 + wm + mi * 16 + g * 4;
            const int b = mbase >> 11, s0 = mbase & 2047;
            #pragma unroll
            for (int ni = 0; ni < 4; ++ni) {
                const int e = n0 + wn + ni * 16 + k15;
                const int qi = e >> 10, h = (e >> 6) & 15, hd = e & 63;
                const int bh = b * 16 + h;
                if (qi == 2) {
                    // V transposed: [bh][d=hd][s], 4 consecutive s packed
                    const u32 lo = cvtpk(acc[mi][ni][0], acc[mi][ni][1]);
                    const u32 hi = cvtpk(acc[mi][ni][2], acc[mi][ni][3]);
                    *(uint2*)&voutb[((size_t)bh * 64 + hd) * SEQ + s0] = make_uint2(lo, hi);
                } else {
                    const float scl = (qi == 0) ? 0.125f : 1.0f;  // fold softmax scale (exact)
                    #pragma unroll
                    for (int r = 0; r < 4; ++r)
                        outb[((size_t)(qi * 64 + bh) * SEQ + s0 + r) * 64 + hd] =
                            f2bf(acc[mi][ni][r] * scl);
                }
            }
        }
    } else {
        #pragma unroll
        for (int mi = 0; mi < 4; ++mi) {
            #pragma unroll
            for (int r = 0; r < 4; ++r) {
                const size_t m = m0 + wm + mi * 16 + g * 4 + r;
                #pragma unroll
                for (int ni = 0; ni < 4; ++ni) {
                    const int e = n0 + wn + ni * 16 + k15;
                    outf[m * 1024 + e] = acc[mi][ni][r] + bias[e];
                }
            }
        }
    }
}

// ---------------------------------------------------------------------------
// Flash attention, bf16 MFMA, swapped operands, 2-phase double-buffered
// K/V staging via global_load_lds (pre-swizzled source, linear LDS dest).
// 256 threads = 4 waves; wave owns 32 q-rows. KVBLK=64.
// ---------------------------------------------------------------------------
__global__ __launch_bounds__(256) void attn_mfma(const ushort_t* __restrict__ qk,
                                                 const ushort_t* __restrict__ vt,
                                                 ushort_t* __restrict__ aout) {
    __shared__ __align__(16) ushort_t Ks[2][64 * 64];
    __shared__ __align__(16) ushort_t Vs[2][64 * 64];   // V^T tiles: [d][key]
    __shared__ __align__(16) ushort_t Pl[4][32 * 64];

    const int t = threadIdx.x, w = t >> 6, lane = t & 63;
    const int k15 = lane & 15, g = lane >> 4;
    const int q0 = blockIdx.x * 128, bh = blockIdx.y;
    const ushort_t* Qp = qk + (size_t)bh * SEQ * 64;
    const ushort_t* Kp = qk + (size_t)(64 + bh) * SEQ * 64;
    const ushort_t* Vp = vt + (size_t)bh * 64 * SEQ;    // [d][s]
    const int wq0 = q0 + w * 32;
    ushort_t* Pw = Pl[w];

    const int srow = t >> 3;   // 0..31
    const int sgrp = t & 7;

    // Q fragments (B-operand: lane&15 = q), resident whole kernel; pre-scaled
    short8 qf[2][2];
    #pragma unroll
    for (int qt = 0; qt < 2; ++qt)
        #pragma unroll
        for (int ks = 0; ks < 2; ++ks)
            qf[qt][ks] = *(const short8*)&Qp[(size_t)(wq0 + qt * 16 + k15) * 64 + ks * 32 + g * 8];

    // prologue: stage tile 0 into buffer 0
    #pragma unroll
    for (int i = 0; i < 2; ++i) {
        const int row = i * 32 + srow;
        const int scb = sgrp ^ (row & 7);
        gload16(&Kp[(size_t)row * 64 + scb * 8], ((char*)Ks) + i * 4096 + t * 16);
        gload16(&Vp[(size_t)row * SEQ + scb * 8], ((char*)Vs) + i * 4096 + t * 16);
    }
    __syncthreads();

    f32x4 o2[4][2] = {};               // O^T: [d-tile][q-tile], col=q=k15
    float mi[2] = {-1e30f, -1e30f}, li[2] = {0.f, 0.f};
    int cur = 0;

    for (int kt = 0; kt < SEQ / 64; ++kt) {
        // issue next tile's staging FIRST (overlaps with compute below)
        if (kt + 1 < SEQ / 64) {
            const int kbn = (kt + 1) * 64;
            #pragma unroll
            for (int i = 0; i < 2; ++i) {
                const int row = i * 32 + srow;
                const int scb = sgrp ^ (row & 7);
                gload16(&Kp[(size_t)(kbn + row) * 64 + scb * 8],
                        ((char*)Ks) + (cur ^ 1) * 8192 + i * 4096 + t * 16);
                gload16(&Vp[(size_t)row * SEQ + kbn + scb * 8],
                        ((char*)Vs) + (cur ^ 1) * 8192 + i * 4096 + t * 16);
            }
        }

        // QK^T swapped: S^T[key][q]; lane holds key = mt*16 + g*4 + r, q = qt*16 + k15
        f32x4 s2[4][2] = {};
        __builtin_amdgcn_s_setprio(1);
        #pragma unroll
        for (int ks = 0; ks < 2; ++ks) {
            short8 kf[4];
            #pragma unroll
            for (int mt = 0; mt < 4; ++mt)
                kf[mt] = *(const short8*)&Ks[cur][swz8(mt * 16 + k15, ks * 32 + g * 8)];
            #pragma unroll
            for (int mt = 0; mt < 4; ++mt)
                #pragma unroll
                for (int qt = 0; qt < 2; ++qt)
                    s2[mt][qt] = __builtin_amdgcn_mfma_f32_16x16x32_bf16(
                        kf[mt], qf[qt][ks], s2[mt][qt], 0, 0, 0);
        }
        __builtin_amdgcn_s_setprio(0);

        // in-lane online softmax (16 keys/lane per qt; row spans 4 g-groups)
        float corr[2];
        #pragma unroll
        for (int qt = 0; qt < 2; ++qt) {
            float vm = s2[0][qt][0];
            #pragma unroll
            for (int mt = 0; mt < 4; ++mt)
                #pragma unroll
                for (int r = 0; r < 4; ++r)
                    vm = fmaxf(vm, s2[mt][qt][r]);
            vm = fmaxf(vm, __shfl_xor(vm, 16));
            vm = fmaxf(vm, __shfl_xor(vm, 32));
            const float mnew = fmaxf(mi[qt], vm);
            corr[qt] = __expf(mi[qt] - mnew);
            mi[qt] = mnew;
            float rs = 0.f;
            #pragma unroll
            for (int mt = 0; mt < 4; ++mt)
                #pragma unroll
                for (int r = 0; r < 4; ++r) {
                    const float e = __expf(s2[mt][qt][r] - mnew);
                    s2[mt][qt][r] = e;
                    rs += e;
                }
            rs += __shfl_xor(rs, 16);
            rs += __shfl_xor(rs, 32);
            li[qt] = li[qt] * corr[qt] + rs;
        }

        // P -> LDS [32 q][64 key] per wave (packed b64, swizzled)
        #pragma unroll
        for (int qt = 0; qt < 2; ++qt) {
            const int row = qt * 16 + k15;
            #pragma unroll
            for (int i = 0; i < 4; ++i) {   // keys 16*i + 4*g .. +3
                const u32 lo = cvtpk(s2[i][qt][0], s2[i][qt][1]);
                const u32 hi = cvtpk(s2[i][qt][2], s2[i][qt][3]);
                const int grp = 2 * i + (g >> 1);
                const int idx = row * 64 + ((grp ^ (row & 7)) << 3) + (g & 1) * 4;
                *(uint2*)&Pw[idx] = make_uint2(lo, hi);
            }
        }

        // rescale O
        #pragma unroll
        for (int mt = 0; mt < 4; ++mt)
            #pragma unroll
            for (int qt = 0; qt < 2; ++qt)
                #pragma unroll
                for (int r = 0; r < 4; ++r)
                    o2[mt][qt][r] *= corr[qt];

        // PV swapped: O^T[d][q] += V^T[d][key] * P^T[key][q]
        __builtin_amdgcn_s_setprio(1);
        #pragma unroll
        for (int ks = 0; ks < 2; ++ks) {
            short8 vb[4], pa[2];
            #pragma unroll
            for (int mt = 0; mt < 4; ++mt)
                vb[mt] = *(const short8*)&Vs[cur][swz8(mt * 16 + k15, ks * 32 + g * 8)];
            #pragma unroll
            for (int qt = 0; qt < 2; ++qt)
                pa[qt] = *(const short8*)&Pw[swz8(qt * 16 + k15, ks * 32 + g * 8)];
            #pragma unroll
            for (int mt = 0; mt < 4; ++mt)
                #pragma unroll
                for (int qt = 0; qt < 2; ++qt)
                    o2[mt][qt] = __builtin_amdgcn_mfma_f32_16x16x32_bf16(
                        vb[mt], pa[qt], o2[mt][qt], 0, 0, 0);
        }
        __builtin_amdgcn_s_setprio(0);

        __syncthreads();   // drains vmcnt (prefetch landed) + protects buffers
        cur ^= 1;
    }

    // epilogue: lane owns q = wq0 + qt*16 + k15, d = mt*16 + g*4 + r (8B stores)
    const int b = bh >> 4, h = bh & 15;
    #pragma unroll
    for (int qt = 0; qt < 2; ++qt) {
        const float inv = 1.0f / li[qt];
        const int q = wq0 + qt * 16 + k15;
        const size_t base = ((size_t)b * SEQ + q) * DIM + h * 64;
        #pragma unroll
        for (int mt = 0; mt < 4; ++mt) {
            const u32 lo = cvtpk(o2[mt][qt][0] * inv, o2[mt][qt][1] * inv);
            const u32 hi = cvtpk(o2[mt][qt][2] * inv, o2[mt][qt][3] * inv);
            *(uint2*)&aout[base + mt * 16 + g * 4] = make_uint2(lo, hi);
        }
    }
}

// ---------------------------------------------------------------------------
extern "C" void kernel_launch(void* const* d_in, const int* in_sizes, int n_in,
                              void* d_out, int out_size, void* d_ws, size_t ws_size,
                              hipStream_t stream) {
    const float* x     = (const float*)d_in[0];   // [4,2048,1024]
    const float* w_qkv = (const float*)d_in[1];   // [3072,1024]
    const float* w_out = (const float*)d_in[2];   // [1024,1024]
    const float* b_out = (const float*)d_in[3];   // [1024]
    float* out = (float*)d_out;

    char* ws = (char*)d_ws;
    ushort_t* xb    = (ushort_t*)ws;                                // 16 MB
    ushort_t* wqkvb = (ushort_t*)(ws + (size_t)16 * 1024 * 1024);   // 6 MB
    ushort_t* woutb = (ushort_t*)(ws + (size_t)22 * 1024 * 1024);   // 2 MB
    ushort_t* qkb   = (ushort_t*)(ws + (size_t)24 * 1024 * 1024);   // 32 MB: [2][64][2048][64]
    ushort_t* vtb   = (ushort_t*)(ws + (size_t)56 * 1024 * 1024);   // 16 MB: [64][64][2048]
    ushort_t* aob   = (ushort_t*)(ws + (size_t)72 * 1024 * 1024);   // 16 MB: [8192][1024]

    cvt_bf16<<<1024, 256, 0, stream>>>(x,     xb,    8192 * 1024 / 8);
    cvt_bf16<<<512,  256, 0, stream>>>(w_qkv, wqkvb, 3072 * 1024 / 8);
    cvt_bf16<<<256,  256, 0, stream>>>(w_out, woutb, 1024 * 1024 / 8);

    gemm_bt<0><<<dim3(24, 64), 256, 0, stream>>>(xb, wqkvb, nullptr, qkb, vtb, nullptr);
    attn_mfma<<<dim3(16, 64), 256, 0, stream>>>(qkb, vtb, aob);
    gemm_bt<1><<<dim3(8, 64), 256, 0, stream>>>(aob, woutb, b_out, nullptr, nullptr, out);
}